// Round 9
// baseline (202.165 us; speedup 1.0000x reference)
//
#include <hip/hip_runtime.h>
#include <hip/hip_bf16.h>

#define Bb 64
#define Ll 200
#define NSs 1000
#define Dd 128
#define Mm 50

__device__ __forceinline__ float bcast_lane(float v, int l) {
    return __int_as_float(__builtin_amdgcn_readlane(__float_as_int(v), l));
}

// ============ fused kernel: blocks [0,200) = ea GEMM, [200,1000) = w softmax ============
// ea: 64 pos/block, 4 waves; wave owns concat rows [w*64,+64) in 2 subs of 32
//     (wave-private wt, no inner barriers). Lane tile: 8 pos x 4 rows
//     (pos {pg+8i}, rows {og+8j}) -> 12 b128 reads per 128 MACs (1.5 B/MAC).
// w : R8 structure, 16 pos/block (4 waves x 4 pos), Mk staged per block.
__global__ void __launch_bounds__(256) kern_wea(
        const int* __restrict__ skills,
        const int* __restrict__ responses,
        const float* __restrict__ k_emb,
        const float* __restrict__ v_emb,
        const float* __restrict__ Mk,
        const float* __restrict__ e_W, const float* __restrict__ e_b,
        const float* __restrict__ a_W, const float* __restrict__ a_b,
        float* __restrict__ w_out,
        float* __restrict__ e_out, float* __restrict__ a_out) {
    __shared__ float smem[25344];                 // 101.4 KB union
    int tid = threadIdx.x;

    if (blockIdx.x >= 200) {
        // ---------------- w branch ----------------
        int blk = blockIdx.x - 200;               // 0..799, 16 pos each
        float (*mk)[Dd + 4] = (float(*)[Dd + 4])smem;          // 50 rows
        float (*kr)[Dd + 4] = (float(*)[Dd + 4])(smem + 6600); // 16 rows

        for (int lin = tid; lin < (Mm * Dd) / 4; lin += 256) {
            float4 f = ((const float4*)Mk)[lin];
            *(float4*)&mk[lin >> 5][(lin & 31) * 4] = f;
        }
        for (int lin = tid; lin < 16 * 32; lin += 256) {
            int r  = lin >> 5;
            int c4 = lin & 31;
            int bl = blk * 16 + r;
            float4 f = ((const float4*)(k_emb + (size_t)skills[bl] * Dd))[c4];
            *(float4*)&kr[r][c4 * 4] = f;
        }
        __syncthreads();

        int wave = tid >> 6, lane = tid & 63;
        int mmr  = (lane < Mm) ? lane : 0;
        float acc[4] = {0.f, 0.f, 0.f, 0.f};
#pragma unroll 2
        for (int q = 0; q < 32; ++q) {
            float4 mkv = *(const float4*)&mk[mmr][q * 4];
#pragma unroll
            for (int i = 0; i < 4; ++i) {
                float4 kv = *(const float4*)&kr[wave * 4 + i][q * 4];
                acc[i] = fmaf(mkv.x, kv.x, acc[i]);
                acc[i] = fmaf(mkv.y, kv.y, acc[i]);
                acc[i] = fmaf(mkv.z, kv.z, acc[i]);
                acc[i] = fmaf(mkv.w, kv.w, acc[i]);
            }
        }
#pragma unroll
        for (int i = 0; i < 4; ++i) {
            float logit = (lane < Mm) ? acc[i] : -1e30f;
            float mx = logit;
            for (int off = 32; off > 0; off >>= 1) mx = fmaxf(mx, __shfl_down(mx, off));
            mx = __shfl(mx, 0);
            float ex = (lane < Mm) ? expf(logit - mx) : 0.f;
            float sm = ex;
            for (int off = 32; off > 0; off >>= 1) sm += __shfl_down(sm, off);
            sm = __shfl(sm, 0);
            int bl = blk * 16 + wave * 4 + i;
            if (lane < Mm) w_out[(size_t)bl * Mm + lane] = ex / sm;
        }
        return;
    }

    // ---------------- ea branch ----------------
    int blk = blockIdx.x;                          // 0..199, 64 pos each
    float (*vt)[Dd + 4] = (float(*)[Dd + 4])smem;          // 64 rows
    float (*wt)[Dd + 4] = (float(*)[Dd + 4])(smem + 8448); // 4 x 32 rows

    // stage 64 gathered v rows (4096 B128 writes, coalesced, conflict-free)
#pragma unroll
    for (int i = 0; i < 8; ++i) {
        int lin = i * 256 + tid;
        int r   = lin >> 5;
        int c4  = lin & 31;
        int bl  = blk * 64 + r;
        int rr  = responses[bl];
        int x   = skills[bl] + NSs * ((rr > -1) ? rr : 0);
        float4 f = ((const float4*)(v_emb + (size_t)x * Dd))[c4];
        *(float4*)&vt[r][c4 * 4] = f;
    }
    __syncthreads();

    int wave = tid >> 6, lane = tid & 63;
    int pg = lane >> 3, og = lane & 7;

    for (int s = 0; s < 2; ++s) {
        int base_row = wave * 64 + s * 32;         // concat space [0,256)
        bool is_e    = base_row < 128;
        const float* W = is_e ? e_W : a_W;
        int wrow0 = is_e ? base_row : base_row - 128;

        // wave stages its 32 weight rows (1024 float4 by 64 lanes)
#pragma unroll
        for (int i = 0; i < 16; ++i) {
            int lin = i * 64 + lane;
            int r   = lin >> 5;
            int c4  = lin & 31;
            float4 f = ((const float4*)(W + (size_t)(wrow0 + r) * Dd))[c4];
            *(float4*)&wt[wave * 32 + r][c4 * 4] = f;
        }
        // wave-private tile: per-wave LDS ordering, no barrier needed

        float acc[8][4] = {};
#pragma unroll 2
        for (int q = 0; q < 32; ++q) {
            float4 av[8], bv[4];
#pragma unroll
            for (int i = 0; i < 8; ++i) av[i] = *(const float4*)&vt[pg + 8 * i][q * 4];
#pragma unroll
            for (int j = 0; j < 4; ++j) bv[j] = *(const float4*)&wt[wave * 32 + og + 8 * j][q * 4];
#pragma unroll
            for (int i = 0; i < 8; ++i)
#pragma unroll
                for (int j = 0; j < 4; ++j) {
                    acc[i][j] = fmaf(av[i].x, bv[j].x, acc[i][j]);
                    acc[i][j] = fmaf(av[i].y, bv[j].y, acc[i][j]);
                    acc[i][j] = fmaf(av[i].z, bv[j].z, acc[i][j]);
                    acc[i][j] = fmaf(av[i].w, bv[j].w, acc[i][j]);
                }
        }

        float* dst = is_e ? e_out : a_out;
#pragma unroll
        for (int j = 0; j < 4; ++j) {
            int row = wrow0 + og + 8 * j;
            float bias = (is_e ? e_b : a_b)[row];
#pragma unroll
            for (int i = 0; i < 8; ++i) {
                int bl = blk * 64 + pg + 8 * i;
                float v = acc[i][j] + bias;
                dst[(size_t)bl * Dd + row] = is_e ? (1.f / (1.f + expf(-v))) : tanhf(v);
            }
        }
    }
}

// ============ scan pass 1: per-chunk affine transfer (P, Q) ============
#define PQ_LOAD(S, tt) do { int _t = (tt);                                   \
    if (_t < T) { size_t _bl = blBase + _t;                                  \
        w##S = (lane < Mm) ? w_ws[_bl * Mm + lane] : 0.f;                    \
        e##S = e_ws[_bl * Dd + d];  a##S = a_ws[_bl * Dd + d]; } } while (0)

#define PQ_BODY(S) do {                                                      \
    _Pragma("unroll")                                                        \
    for (int m = 0; m < Mm; ++m) {                                           \
        float wm = bcast_lane(w##S, m);                                      \
        float A  = fmaf(-wm, e##S, 1.f);                                     \
        Q[m] = fmaf(A, Q[m], wm * a##S);                                     \
        P[m] *= A; } } while (0)

__global__ void __launch_bounds__(128) kern_scan_pq(
        const float* __restrict__ w_ws,
        const float* __restrict__ e_ws,
        const float* __restrict__ a_ws,
        float* __restrict__ P_ws, float* __restrict__ Q_ws,
        int C, int T) {
    int b = blockIdx.x / C, c = blockIdx.x % C;
    int d = threadIdx.x;
    int lane = d & 63;
    float P[Mm], Q[Mm];
#pragma unroll
    for (int m = 0; m < Mm; ++m) { P[m] = 1.f; Q[m] = 0.f; }

    size_t blBase = (size_t)b * Ll + (size_t)c * T;
    float w0 = 0.f, e0 = 0.f, a0 = 0.f;
    float w1 = 0.f, e1 = 0.f, a1 = 0.f;
    float w2 = 0.f, e2 = 0.f, a2 = 0.f;
    PQ_LOAD(0, 0);
    PQ_LOAD(1, 1);
    for (int tt = 0; tt < T; tt += 3) {
        PQ_LOAD(2, tt + 2);  PQ_BODY(0);
        if (tt + 1 < T) { PQ_LOAD(0, tt + 3);  PQ_BODY(1); }
        if (tt + 2 < T) { PQ_LOAD(1, tt + 4);  PQ_BODY(2); }
    }
    size_t base = ((size_t)(b * C + c)) * (Mm * Dd) + d;
#pragma unroll
    for (int m = 0; m < Mm; ++m) {
        P_ws[base + m * Dd] = P[m];
        Q_ws[base + m * Dd] = Q[m];
    }
}

// ============ scan pass 2: chunk-boundary combine (compile-time C) ============
template <int CC>
__global__ void kern_scan_comb_t(
        const float* __restrict__ Mv0,
        const float* __restrict__ P_ws, const float* __restrict__ Q_ws,
        float* __restrict__ S_ws) {
    int idx = blockIdx.x * 256 + threadIdx.x;
    int b   = idx / (Mm * Dd);
    int md  = idx % (Mm * Dd);
    float Pr[CC - 1], Qr[CC - 1];
#pragma unroll
    for (int c = 0; c < CC - 1; ++c) {
        size_t pq = ((size_t)(b * CC + c)) * (Mm * Dd) + md;
        Pr[c] = P_ws[pq];
        Qr[c] = Q_ws[pq];
    }
    float s = Mv0[md];
#pragma unroll
    for (int c = 0; c < CC - 1; ++c) {
        s = fmaf(Pr[c], s, Qr[c]);
        S_ws[((size_t)(b * (CC - 1) + c)) * (Mm * Dd) + md] = s;
    }
}

// ============ scan pass 3: rescan chunk from known start, emit read ============
#define RD_BODY(S, tt) do {                                                  \
    float acc0 = 0.f, acc1 = 0.f;                                            \
    _Pragma("unroll")                                                        \
    for (int m = 0; m < Mm; m += 2) {                                        \
        float wm0 = bcast_lane(w##S, m);                                     \
        float wm1 = bcast_lane(w##S, m + 1);                                 \
        acc0 = fmaf(wm0, mv[m], acc0);                                       \
        mv[m] = fmaf(wm0, fmaf(-e##S, mv[m], a##S), mv[m]);                  \
        acc1 = fmaf(wm1, mv[m + 1], acc1);                                   \
        mv[m + 1] = fmaf(wm1, fmaf(-e##S, mv[m + 1], a##S), mv[m + 1]);      \
    }                                                                        \
    read_ws[(blBase + (tt)) * Dd + d] = acc0 + acc1;                         \
    } while (0)

__global__ void __launch_bounds__(128) kern_scan_rd(
        const float* __restrict__ Mv0,
        const float* __restrict__ S_ws,
        const float* __restrict__ w_ws,
        const float* __restrict__ e_ws,
        const float* __restrict__ a_ws,
        float* __restrict__ read_ws,
        int C, int T) {
    int b = blockIdx.x / C, c = blockIdx.x % C;
    int d = threadIdx.x;
    int lane = d & 63;
    float mv[Mm];
    if (c == 0) {
#pragma unroll
        for (int m = 0; m < Mm; ++m) mv[m] = Mv0[m * Dd + d];
    } else {
        size_t sb = ((size_t)(b * (C - 1) + (c - 1))) * (Mm * Dd) + d;
#pragma unroll
        for (int m = 0; m < Mm; ++m) mv[m] = S_ws[sb + m * Dd];
    }

    size_t blBase = (size_t)b * Ll + (size_t)c * T;
    float w0 = 0.f, e0 = 0.f, a0 = 0.f;
    float w1 = 0.f, e1 = 0.f, a1 = 0.f;
    float w2 = 0.f, e2 = 0.f, a2 = 0.f;
    PQ_LOAD(0, 0);
    PQ_LOAD(1, 1);
    for (int tt = 0; tt < T; tt += 3) {
        PQ_LOAD(2, tt + 2);  RD_BODY(0, tt);
        if (tt + 1 < T) { PQ_LOAD(0, tt + 3);  RD_BODY(1, tt + 1); }
        if (tt + 2 < T) { PQ_LOAD(1, tt + 4);  RD_BODY(2, tt + 2); }
    }
}

// ============ kernel 4: p = sigmoid(tanh([read|k]@fW^T+fb) @ pW^T + pb) ============
// 64 pos/block, 4 waves; wave owns f_W rows [w*32,+32), K staged in 2 halves
// (wave-private wt, no inner barriers). Lane tile: 8 pos x 4 rows.
__global__ void __launch_bounds__(256) kern_out(
        const int* __restrict__ skills,
        const float* __restrict__ read_ws,
        const float* __restrict__ k_emb,
        const float* __restrict__ f_W, const float* __restrict__ f_b,
        const float* __restrict__ p_W, const float* __restrict__ p_b,
        float* __restrict__ out) {
    __shared__ float ct[64][2 * Dd + 4];       // 66.6 KB, stride 260
    __shared__ float wt[4][32][Dd + 4];        // 67.6 KB
    __shared__ float pf[64][4];
    int tid = threadIdx.x;
    int blk = blockIdx.x;

    // stage 64 rows of [read|k]: 4096 float4
#pragma unroll
    for (int i = 0; i < 16; ++i) {
        int lin = i * 256 + tid;
        int r   = lin >> 6;
        int c4  = lin & 63;
        int idx = blk * 64 + r;
        int b   = idx / (Ll - 1);
        int l   = idx % (Ll - 1) + 1;
        int bl  = b * Ll + l;
        float4 f;
        if (c4 < 32) f = ((const float4*)(read_ws + (size_t)bl * Dd))[c4];
        else         f = ((const float4*)(k_emb + (size_t)skills[bl] * Dd))[c4 - 32];
        *(float4*)&ct[r][c4 * 4] = f;
    }
    __syncthreads();

    int wave = tid >> 6, lane = tid & 63;
    int pg = lane >> 3, og = lane & 7;

    float acc[8][4] = {};
    for (int h = 0; h < 2; ++h) {
        // wave stages its 32 f_W rows, K cols [h*128,+128) (1024 float4)
#pragma unroll
        for (int i = 0; i < 16; ++i) {
            int lin = i * 64 + lane;
            int r   = lin >> 5;
            int c4  = lin & 31;
            float4 f = ((const float4*)(f_W + (size_t)(wave * 32 + r) * (2 * Dd)))[h * 32 + c4];
            *(float4*)&wt[wave][r][c4 * 4] = f;
        }
        // wave-private tile: no barrier
#pragma unroll 2
        for (int q = 0; q < 32; ++q) {
            int k = h * 128 + q * 4;
            float4 av[8], bv[4];
#pragma unroll
            for (int i = 0; i < 8; ++i) av[i] = *(const float4*)&ct[pg + 8 * i][k];
#pragma unroll
            for (int j = 0; j < 4; ++j) bv[j] = *(const float4*)&wt[wave][og + 8 * j][q * 4];
#pragma unroll
            for (int i = 0; i < 8; ++i)
#pragma unroll
                for (int j = 0; j < 4; ++j) {
                    acc[i][j] = fmaf(av[i].x, bv[j].x, acc[i][j]);
                    acc[i][j] = fmaf(av[i].y, bv[j].y, acc[i][j]);
                    acc[i][j] = fmaf(av[i].z, bv[j].z, acc[i][j]);
                    acc[i][j] = fmaf(av[i].w, bv[j].w, acc[i][j]);
                }
        }
    }

    // epilogue: tanh + p-head, reduce over og (width-8), then across waves
    float ppart[8] = {};
#pragma unroll
    for (int j = 0; j < 4; ++j) {
        int row = wave * 32 + og + 8 * j;
        float fb = f_b[row];
        float pw = p_W[row];
#pragma unroll
        for (int i = 0; i < 8; ++i)
            ppart[i] = fmaf(tanhf(acc[i][j] + fb), pw, ppart[i]);
    }
#pragma unroll
    for (int i = 0; i < 8; ++i) {
        float v = ppart[i];
        for (int off = 4; off > 0; off >>= 1) v += __shfl_down(v, off, 8);
        if (og == 0) pf[pg + 8 * i][wave] = v;
    }
    __syncthreads();
    if (tid < 64) {
        float s = pf[tid][0] + pf[tid][1] + pf[tid][2] + pf[tid][3] + p_b[0];
        out[blk * 64 + tid] = 1.f / (1.f + expf(-s));
    }
}

extern "C" void kernel_launch(void* const* d_in, const int* in_sizes, int n_in,
                              void* d_out, int out_size, void* d_ws, size_t ws_size,
                              hipStream_t stream) {
    const int*   skills    = (const int*)  d_in[0];
    const int*   responses = (const int*)  d_in[1];
    const float* k_emb     = (const float*)d_in[2];
    const float* v_emb     = (const float*)d_in[3];
    const float* Mk        = (const float*)d_in[4];
    const float* Mv0       = (const float*)d_in[5];
    const float* e_W       = (const float*)d_in[6];
    const float* e_b       = (const float*)d_in[7];
    const float* a_W       = (const float*)d_in[8];
    const float* a_b       = (const float*)d_in[9];
    const float* f_W       = (const float*)d_in[10];
    const float* f_b       = (const float*)d_in[11];
    const float* p_W       = (const float*)d_in[12];
    const float* p_b       = (const float*)d_in[13];
    (void)in_sizes; (void)n_in; (void)out_size;

    float* out = (float*)d_out;

    float* ws      = (float*)d_ws;
    float* w_ws    = ws;                                  // B*L*M
    float* e_ws    = w_ws + (size_t)Bb * Ll * Mm;         // B*L*D
    float* a_ws    = e_ws + (size_t)Bb * Ll * Dd;         // B*L*D
    float* read_ws = a_ws + (size_t)Bb * Ll * Dd;         // B*L*D
    float* extra   = read_ws + (size_t)Bb * Ll * Dd;

    const size_t baseF = (size_t)Bb * Ll * Mm + 3 * (size_t)Bb * Ll * Dd;
    const size_t BMD   = (size_t)Bb * Mm * Dd;
    int C = 1;
    const int cands[3] = {8, 5, 2};
    for (int i = 0; i < 3; ++i) {
        size_t need = (baseF + BMD * (3 * (size_t)cands[i] - 1)) * sizeof(float);
        if (ws_size >= need) { C = cands[i]; break; }
    }
    int T = Ll / C;
    float* P_ws = extra;
    float* Q_ws = P_ws + BMD * C;
    float* S_ws = Q_ws + BMD * C;

    kern_wea<<<200 + Bb * Ll / 16, 256, 0, stream>>>(skills, responses, k_emb, v_emb, Mk,
                                                     e_W, e_b, a_W, a_b, w_ws, e_ws, a_ws);
    if (C > 1) {
        kern_scan_pq<<<Bb * C, 128, 0, stream>>>(w_ws, e_ws, a_ws, P_ws, Q_ws, C, T);
        int cgrid = (int)(BMD / 256);
        if      (C == 8) kern_scan_comb_t<8><<<cgrid, 256, 0, stream>>>(Mv0, P_ws, Q_ws, S_ws);
        else if (C == 5) kern_scan_comb_t<5><<<cgrid, 256, 0, stream>>>(Mv0, P_ws, Q_ws, S_ws);
        else             kern_scan_comb_t<2><<<cgrid, 256, 0, stream>>>(Mv0, P_ws, Q_ws, S_ws);
    }
    kern_scan_rd<<<Bb * C, 128, 0, stream>>>(Mv0, S_ws, w_ws, e_ws, a_ws, read_ws, C, T);
    kern_out<<<Bb * (Ll - 1) / 64, 256, 0, stream>>>(skills, read_ws, k_emb,
                                                     f_W, f_b, p_W, p_b, out);
}

// Round 10
// 184.359 us; speedup vs baseline: 1.0966x; 1.0966x over previous
//
#include <hip/hip_runtime.h>
#include <hip/hip_bf16.h>

#define Bb 64
#define Ll 200
#define NSs 1000
#define Dd 128
#define Mm 50

__device__ __forceinline__ float bcast_lane(float v, int l) {
    return __int_as_float(__builtin_amdgcn_readlane(__float_as_int(v), l));
}

// ============ fused kernel: blocks [0,400) = ea GEMM (32 pos), [400,1200) = w softmax (16 pos) ============
// Both branches fit one 12672-float (50.7 KB) LDS union -> 3 blocks/CU.
// ea: R8 structure — wave owns concat rows [w*64,+64) in 4 subs of 16 (wave-private
//     wt, no inner barriers); lane tile 4 pos x 2 rows (pos {pg+8i}, rows {og+8j}).
// w : R8 structure — Mk staged per block, 4 waves x 4 pos.
__global__ void __launch_bounds__(256) kern_wea(
        const int* __restrict__ skills,
        const int* __restrict__ responses,
        const float* __restrict__ k_emb,
        const float* __restrict__ v_emb,
        const float* __restrict__ Mk,
        const float* __restrict__ e_W, const float* __restrict__ e_b,
        const float* __restrict__ a_W, const float* __restrict__ a_b,
        float* __restrict__ w_out,
        float* __restrict__ e_out, float* __restrict__ a_out) {
    __shared__ float smem[12672];                 // 50.7 KB union
    int tid = threadIdx.x;

    if (blockIdx.x >= 400) {
        // ---------------- w branch: 16 pos ----------------
        int blk = blockIdx.x - 400;               // 0..799
        float (*mk)[Dd + 4] = (float(*)[Dd + 4])smem;          // 50 rows  (6600 f)
        float (*kr)[Dd + 4] = (float(*)[Dd + 4])(smem + 6600); // 16 rows  (2112 f)

        for (int lin = tid; lin < (Mm * Dd) / 4; lin += 256) {   // 1600 float4
            float4 f = ((const float4*)Mk)[lin];
            *(float4*)&mk[lin >> 5][(lin & 31) * 4] = f;
        }
        for (int lin = tid; lin < 16 * 32; lin += 256) {          // 512 float4
            int r  = lin >> 5;
            int c4 = lin & 31;
            int bl = blk * 16 + r;
            float4 f = ((const float4*)(k_emb + (size_t)skills[bl] * Dd))[c4];
            *(float4*)&kr[r][c4 * 4] = f;
        }
        __syncthreads();

        int wave = tid >> 6, lane = tid & 63;
        int mmr  = (lane < Mm) ? lane : 0;
        float acc[4] = {0.f, 0.f, 0.f, 0.f};
#pragma unroll 2
        for (int q = 0; q < 32; ++q) {
            float4 mkv = *(const float4*)&mk[mmr][q * 4];
#pragma unroll
            for (int i = 0; i < 4; ++i) {
                float4 kv = *(const float4*)&kr[wave * 4 + i][q * 4];
                acc[i] = fmaf(mkv.x, kv.x, acc[i]);
                acc[i] = fmaf(mkv.y, kv.y, acc[i]);
                acc[i] = fmaf(mkv.z, kv.z, acc[i]);
                acc[i] = fmaf(mkv.w, kv.w, acc[i]);
            }
        }
#pragma unroll
        for (int i = 0; i < 4; ++i) {
            float logit = (lane < Mm) ? acc[i] : -1e30f;
            float mx = logit;
            for (int off = 32; off > 0; off >>= 1) mx = fmaxf(mx, __shfl_down(mx, off));
            mx = __shfl(mx, 0);
            float ex = (lane < Mm) ? expf(logit - mx) : 0.f;
            float sm = ex;
            for (int off = 32; off > 0; off >>= 1) sm += __shfl_down(sm, off);
            sm = __shfl(sm, 0);
            int bl = blk * 16 + wave * 4 + i;
            if (lane < Mm) w_out[(size_t)bl * Mm + lane] = ex / sm;
        }
        return;
    }

    // ---------------- ea branch: 32 pos ----------------
    int blk = blockIdx.x;                          // 0..399
    float (*vt)[Dd + 4] = (float(*)[Dd + 4])smem;          // 32 rows (4224 f)
    float (*wt)[Dd + 4] = (float(*)[Dd + 4])(smem + 4224); // 4 x 16 rows (8448 f)

#pragma unroll
    for (int i = 0; i < 4; ++i) {
        int lin = i * 256 + tid;
        int r   = lin >> 5;
        int c4  = lin & 31;
        int bl  = blk * 32 + r;
        int rr  = responses[bl];
        int x   = skills[bl] + NSs * ((rr > -1) ? rr : 0);
        float4 f = ((const float4*)(v_emb + (size_t)x * Dd))[c4];
        *(float4*)&vt[r][c4 * 4] = f;
    }
    __syncthreads();

    int wave = tid >> 6, lane = tid & 63;
    int pg = lane >> 3, og = lane & 7;

    for (int s = 0; s < 4; ++s) {
        int base_row = wave * 64 + s * 16;            // concat space [0,256)
        bool is_e    = base_row < 128;
        const float* W = is_e ? e_W : a_W;
        int wrow0 = is_e ? base_row : base_row - 128;

        // wave stages its 16 weight rows (512 float4 by 64 lanes)
#pragma unroll
        for (int i = 0; i < 8; ++i) {
            int lin = i * 64 + lane;
            int r   = lin >> 5;
            int c4  = lin & 31;
            float4 f = ((const float4*)(W + (size_t)(wrow0 + r) * Dd))[c4];
            *(float4*)&wt[wave * 16 + r][c4 * 4] = f;
        }
        // wave-private tile: per-wave LDS ordering makes a barrier unnecessary

        float acc[4][2] = {};
#pragma unroll 2
        for (int q = 0; q < 32; ++q) {
            float4 av[4], bv[2];
#pragma unroll
            for (int i = 0; i < 4; ++i) av[i] = *(const float4*)&vt[pg + 8 * i][q * 4];
#pragma unroll
            for (int j = 0; j < 2; ++j) bv[j] = *(const float4*)&wt[wave * 16 + og + 8 * j][q * 4];
#pragma unroll
            for (int i = 0; i < 4; ++i)
#pragma unroll
                for (int j = 0; j < 2; ++j) {
                    acc[i][j] = fmaf(av[i].x, bv[j].x, acc[i][j]);
                    acc[i][j] = fmaf(av[i].y, bv[j].y, acc[i][j]);
                    acc[i][j] = fmaf(av[i].z, bv[j].z, acc[i][j]);
                    acc[i][j] = fmaf(av[i].w, bv[j].w, acc[i][j]);
                }
        }

        float* dst = is_e ? e_out : a_out;
#pragma unroll
        for (int j = 0; j < 2; ++j) {
            int row = wrow0 + og + 8 * j;
            float bias = (is_e ? e_b : a_b)[row];
#pragma unroll
            for (int i = 0; i < 4; ++i) {
                int bl = blk * 32 + pg + 8 * i;
                float v = acc[i][j] + bias;
                dst[(size_t)bl * Dd + row] = is_e ? (1.f / (1.f + expf(-v))) : tanhf(v);
            }
        }
    }
}

// ============ scan pass 1: per-chunk affine transfer (P, Q) ============
#define PQ_LOAD(S, tt) do { int _t = (tt);                                   \
    if (_t < T) { size_t _bl = blBase + _t;                                  \
        w##S = (lane < Mm) ? w_ws[_bl * Mm + lane] : 0.f;                    \
        e##S = e_ws[_bl * Dd + d];  a##S = a_ws[_bl * Dd + d]; } } while (0)

#define PQ_BODY(S) do {                                                      \
    _Pragma("unroll")                                                        \
    for (int m = 0; m < Mm; ++m) {                                           \
        float wm = bcast_lane(w##S, m);                                      \
        float A  = fmaf(-wm, e##S, 1.f);                                     \
        Q[m] = fmaf(A, Q[m], wm * a##S);                                     \
        P[m] *= A; } } while (0)

__global__ void __launch_bounds__(128) kern_scan_pq(
        const float* __restrict__ w_ws,
        const float* __restrict__ e_ws,
        const float* __restrict__ a_ws,
        float* __restrict__ P_ws, float* __restrict__ Q_ws,
        int C, int T) {
    int b = blockIdx.x / C, c = blockIdx.x % C;
    int d = threadIdx.x;
    int lane = d & 63;
    float P[Mm], Q[Mm];
#pragma unroll
    for (int m = 0; m < Mm; ++m) { P[m] = 1.f; Q[m] = 0.f; }

    size_t blBase = (size_t)b * Ll + (size_t)c * T;
    float w0 = 0.f, e0 = 0.f, a0 = 0.f;
    float w1 = 0.f, e1 = 0.f, a1 = 0.f;
    float w2 = 0.f, e2 = 0.f, a2 = 0.f;
    PQ_LOAD(0, 0);
    PQ_LOAD(1, 1);
    for (int tt = 0; tt < T; tt += 3) {
        PQ_LOAD(2, tt + 2);  PQ_BODY(0);
        if (tt + 1 < T) { PQ_LOAD(0, tt + 3);  PQ_BODY(1); }
        if (tt + 2 < T) { PQ_LOAD(1, tt + 4);  PQ_BODY(2); }
    }
    size_t base = ((size_t)(b * C + c)) * (Mm * Dd) + d;
#pragma unroll
    for (int m = 0; m < Mm; ++m) {
        P_ws[base + m * Dd] = P[m];
        Q_ws[base + m * Dd] = Q[m];
    }
}

// ============ scan pass 2: chunk-boundary combine (compile-time C) ============
template <int CC>
__global__ void kern_scan_comb_t(
        const float* __restrict__ Mv0,
        const float* __restrict__ P_ws, const float* __restrict__ Q_ws,
        float* __restrict__ S_ws) {
    int idx = blockIdx.x * 256 + threadIdx.x;
    int b   = idx / (Mm * Dd);
    int md  = idx % (Mm * Dd);
    float Pr[CC - 1], Qr[CC - 1];
#pragma unroll
    for (int c = 0; c < CC - 1; ++c) {
        size_t pq = ((size_t)(b * CC + c)) * (Mm * Dd) + md;
        Pr[c] = P_ws[pq];
        Qr[c] = Q_ws[pq];
    }
    float s = Mv0[md];
#pragma unroll
    for (int c = 0; c < CC - 1; ++c) {
        s = fmaf(Pr[c], s, Qr[c]);
        S_ws[((size_t)(b * (CC - 1) + c)) * (Mm * Dd) + md] = s;
    }
}

// ============ scan pass 3: rescan chunk from known start, emit read ============
#define RD_BODY(S, tt) do {                                                  \
    float acc0 = 0.f, acc1 = 0.f;                                            \
    _Pragma("unroll")                                                        \
    for (int m = 0; m < Mm; m += 2) {                                        \
        float wm0 = bcast_lane(w##S, m);                                     \
        float wm1 = bcast_lane(w##S, m + 1);                                 \
        acc0 = fmaf(wm0, mv[m], acc0);                                       \
        mv[m] = fmaf(wm0, fmaf(-e##S, mv[m], a##S), mv[m]);                  \
        acc1 = fmaf(wm1, mv[m + 1], acc1);                                   \
        mv[m + 1] = fmaf(wm1, fmaf(-e##S, mv[m + 1], a##S), mv[m + 1]);      \
    }                                                                        \
    read_ws[(blBase + (tt)) * Dd + d] = acc0 + acc1;                         \
    } while (0)

__global__ void __launch_bounds__(128) kern_scan_rd(
        const float* __restrict__ Mv0,
        const float* __restrict__ S_ws,
        const float* __restrict__ w_ws,
        const float* __restrict__ e_ws,
        const float* __restrict__ a_ws,
        float* __restrict__ read_ws,
        int C, int T) {
    int b = blockIdx.x / C, c = blockIdx.x % C;
    int d = threadIdx.x;
    int lane = d & 63;
    float mv[Mm];
    if (c == 0) {
#pragma unroll
        for (int m = 0; m < Mm; ++m) mv[m] = Mv0[m * Dd + d];
    } else {
        size_t sb = ((size_t)(b * (C - 1) + (c - 1))) * (Mm * Dd) + d;
#pragma unroll
        for (int m = 0; m < Mm; ++m) mv[m] = S_ws[sb + m * Dd];
    }

    size_t blBase = (size_t)b * Ll + (size_t)c * T;
    float w0 = 0.f, e0 = 0.f, a0 = 0.f;
    float w1 = 0.f, e1 = 0.f, a1 = 0.f;
    float w2 = 0.f, e2 = 0.f, a2 = 0.f;
    PQ_LOAD(0, 0);
    PQ_LOAD(1, 1);
    for (int tt = 0; tt < T; tt += 3) {
        PQ_LOAD(2, tt + 2);  RD_BODY(0, tt);
        if (tt + 1 < T) { PQ_LOAD(0, tt + 3);  RD_BODY(1, tt + 1); }
        if (tt + 2 < T) { PQ_LOAD(1, tt + 4);  RD_BODY(2, tt + 2); }
    }
}

// ============ kernel 4: p = sigmoid(tanh([read|k]@fW^T+fb) @ pW^T + pb) ============
// R8 version: 32 pos/block, 4 waves; wave owns f_W rows [w*32,+32) in 2 subs of
// 16; lane tile 4 pos x 2 rows; wt wave-private, no inner barriers.
__global__ void __launch_bounds__(256) kern_out(
        const int* __restrict__ skills,
        const float* __restrict__ read_ws,
        const float* __restrict__ k_emb,
        const float* __restrict__ f_W, const float* __restrict__ f_b,
        const float* __restrict__ p_W, const float* __restrict__ p_b,
        float* __restrict__ out) {
    __shared__ float ct[32][2 * Dd + 4];       // 33.3 KB
    __shared__ float wt[4][16][Dd + 4];        // 33.8 KB
    __shared__ float pf[32][8];
    int tid = threadIdx.x;
    int blk = blockIdx.x;

#pragma unroll
    for (int i = 0; i < 8; ++i) {
        int lin = i * 256 + tid;
        int r   = lin >> 6;
        int c4  = lin & 63;
        int idx = blk * 32 + r;
        int b   = idx / (Ll - 1);
        int l   = idx % (Ll - 1) + 1;
        int bl  = b * Ll + l;
        float4 f;
        if (c4 < 32) f = ((const float4*)(read_ws + (size_t)bl * Dd))[c4];
        else         f = ((const float4*)(k_emb + (size_t)skills[bl] * Dd))[c4 - 32];
        *(float4*)&ct[r][c4 * 4] = f;
    }
    ((float*)pf)[tid] = 0.f;
    __syncthreads();

    int wave = tid >> 6, lane = tid & 63;
    int pg = lane >> 3, og = lane & 7;

    float ppart[4] = {0.f, 0.f, 0.f, 0.f};
    for (int sub = 0; sub < 2; ++sub) {
        float acc[4][2] = {};
        for (int h = 0; h < 2; ++h) {
#pragma unroll
            for (int i = 0; i < 8; ++i) {
                int lin = i * 64 + lane;
                int r   = lin >> 5;
                int c4  = lin & 31;
                float4 f = ((const float4*)(f_W +
                            (size_t)(wave * 32 + sub * 16 + r) * (2 * Dd)))[h * 32 + c4];
                *(float4*)&wt[wave][r][c4 * 4] = f;
            }
            // wave-private tile: no barrier
#pragma unroll 2
            for (int q = 0; q < 32; ++q) {
                int k = h * 128 + q * 4;
                float4 av[4], bv[2];
#pragma unroll
                for (int i = 0; i < 4; ++i) av[i] = *(const float4*)&ct[pg + 8 * i][k];
#pragma unroll
                for (int j = 0; j < 2; ++j) bv[j] = *(const float4*)&wt[wave][og + 8 * j][q * 4];
#pragma unroll
                for (int i = 0; i < 4; ++i)
#pragma unroll
                    for (int j = 0; j < 2; ++j) {
                        acc[i][j] = fmaf(av[i].x, bv[j].x, acc[i][j]);
                        acc[i][j] = fmaf(av[i].y, bv[j].y, acc[i][j]);
                        acc[i][j] = fmaf(av[i].z, bv[j].z, acc[i][j]);
                        acc[i][j] = fmaf(av[i].w, bv[j].w, acc[i][j]);
                    }
            }
        }
#pragma unroll
        for (int j = 0; j < 2; ++j) {
            int row = wave * 32 + sub * 16 + og + 8 * j;
            float fb = f_b[row];
            float pw = p_W[row];
#pragma unroll
            for (int i = 0; i < 4; ++i)
                ppart[i] = fmaf(tanhf(acc[i][j] + fb), pw, ppart[i]);
        }
    }
#pragma unroll
    for (int i = 0; i < 4; ++i) {
        float v = ppart[i];
        for (int off = 4; off > 0; off >>= 1) v += __shfl_down(v, off, 8);
        if (og == 0) pf[pg + 8 * i][wave] = v;
    }
    __syncthreads();
    if (tid < 32) {
        float s = pf[tid][0] + pf[tid][1] + pf[tid][2] + pf[tid][3] + p_b[0];
        out[blk * 32 + tid] = 1.f / (1.f + expf(-s));
    }
}

extern "C" void kernel_launch(void* const* d_in, const int* in_sizes, int n_in,
                              void* d_out, int out_size, void* d_ws, size_t ws_size,
                              hipStream_t stream) {
    const int*   skills    = (const int*)  d_in[0];
    const int*   responses = (const int*)  d_in[1];
    const float* k_emb     = (const float*)d_in[2];
    const float* v_emb     = (const float*)d_in[3];
    const float* Mk        = (const float*)d_in[4];
    const float* Mv0       = (const float*)d_in[5];
    const float* e_W       = (const float*)d_in[6];
    const float* e_b       = (const float*)d_in[7];
    const float* a_W       = (const float*)d_in[8];
    const float* a_b       = (const float*)d_in[9];
    const float* f_W       = (const float*)d_in[10];
    const float* f_b       = (const float*)d_in[11];
    const float* p_W       = (const float*)d_in[12];
    const float* p_b       = (const float*)d_in[13];
    (void)in_sizes; (void)n_in; (void)out_size;

    float* out = (float*)d_out;

    float* ws      = (float*)d_ws;
    float* w_ws    = ws;                                  // B*L*M
    float* e_ws    = w_ws + (size_t)Bb * Ll * Mm;         // B*L*D
    float* a_ws    = e_ws + (size_t)Bb * Ll * Dd;         // B*L*D
    float* read_ws = a_ws + (size_t)Bb * Ll * Dd;         // B*L*D
    float* extra   = read_ws + (size_t)Bb * Ll * Dd;

    const size_t baseF = (size_t)Bb * Ll * Mm + 3 * (size_t)Bb * Ll * Dd;
    const size_t BMD   = (size_t)Bb * Mm * Dd;
    int C = 1;
    const int cands[3] = {8, 5, 2};
    for (int i = 0; i < 3; ++i) {
        size_t need = (baseF + BMD * (3 * (size_t)cands[i] - 1)) * sizeof(float);
        if (ws_size >= need) { C = cands[i]; break; }
    }
    int T = Ll / C;
    float* P_ws = extra;
    float* Q_ws = P_ws + BMD * C;
    float* S_ws = Q_ws + BMD * C;

    kern_wea<<<400 + Bb * Ll / 16, 256, 0, stream>>>(skills, responses, k_emb, v_emb, Mk,
                                                     e_W, e_b, a_W, a_b, w_ws, e_ws, a_ws);
    if (C > 1) {
        kern_scan_pq<<<Bb * C, 128, 0, stream>>>(w_ws, e_ws, a_ws, P_ws, Q_ws, C, T);
        int cgrid = (int)(BMD / 256);
        if      (C == 8) kern_scan_comb_t<8><<<cgrid, 256, 0, stream>>>(Mv0, P_ws, Q_ws, S_ws);
        else if (C == 5) kern_scan_comb_t<5><<<cgrid, 256, 0, stream>>>(Mv0, P_ws, Q_ws, S_ws);
        else             kern_scan_comb_t<2><<<cgrid, 256, 0, stream>>>(Mv0, P_ws, Q_ws, S_ws);
    }
    kern_scan_rd<<<Bb * C, 128, 0, stream>>>(Mv0, S_ws, w_ws, e_ws, a_ws, read_ws, C, T);
    kern_out<<<Bb * (Ll - 1) / 32, 256, 0, stream>>>(skills, read_ws, k_emb,
                                                     f_W, f_b, p_W, p_b, out);
}